// Round 1
// baseline (157.958 us; speedup 1.0000x reference)
//
#include <hip/hip_runtime.h>

// TvarLayer: out[b, (n*C+c)*9+k, l] = (p_k*W[n,c,k] - mean_k(p*W))^2 / sum_k(W[n,c,k]) + Bbias[n,c]
// B=4, N=8, C=8, K=9 (3x3, pad 1, stride 1), H=W=128, L=16384.
// Write-BW-bound: 151 MB out vs 2 MB in.

#define BB 4
#define NN 8
#define CC 8
#define KK 9
#define HH 128
#define WW 128
#define LL (HH * WW)

typedef float vf4 __attribute__((ext_vector_type(4)));

__global__ __launch_bounds__(256) void tvar_kernel(
    const float* __restrict__ arr,
    const float* __restrict__ Wt,
    const float* __restrict__ Bb,
    float* __restrict__ out)
{
    const int tid = blockIdx.x * blockDim.x + threadIdx.x;
    // layout: [b][c][h][w4] — w4 indexes 4-wide column chunks (32 per row)
    const int w4 = tid & 31;
    const int h  = (tid >> 5) & 127;
    const int c  = (tid >> 12) & 7;   // uniform within a 256-thread block
    const int b  = tid >> 15;

    // Stage this c's weights: W[n][c][k], 1/size[n][c], Bbias[n][c]
    __shared__ float sW[NN][KK];
    __shared__ float sInv[NN];
    __shared__ float sBias[NN];
    const int lt = threadIdx.x;
    if (lt < NN * KK) {
        const int n = lt / KK, k = lt - n * KK;
        sW[n][k] = Wt[(n * CC + c) * KK + k];
    }
    __syncthreads();
    if (lt < NN) {
        float s = 0.f;
        #pragma unroll
        for (int k = 0; k < KK; ++k) s += sW[lt][k];
        sInv[lt]  = 1.0f / s;
        sBias[lt] = Bb[lt * CC + c];
    }
    __syncthreads();

    // Load 3x6 patch (rows h-1..h+1, cols ws-1..ws+4), zero-padded.
    const int ws = w4 << 2;
    const float* abase = arr + (size_t)((b * CC + c) * HH) * WW;
    float p[3][6];
    #pragma unroll
    for (int r = 0; r < 3; ++r) {
        const int hh = h + r - 1;
        if (hh >= 0 && hh < HH) {
            const float* row = abase + hh * WW + ws;
            const float4 v = *(const float4*)row;          // ws is 16B-aligned
            p[r][1] = v.x; p[r][2] = v.y; p[r][3] = v.z; p[r][4] = v.w;
            p[r][0] = (ws > 0)       ? row[-1] : 0.f;
            p[r][5] = (ws + 4 < WW)  ? row[4]  : 0.f;
        } else {
            #pragma unroll
            for (int j = 0; j < 6; ++j) p[r][j] = 0.f;
        }
    }

    float* obase = out + (size_t)b * (NN * CC * KK) * LL + (size_t)(h * WW + ws);
    const float inv9 = 1.0f / 9.0f;

    #pragma unroll
    for (int n = 0; n < NN; ++n) {
        float w9[KK];
        #pragma unroll
        for (int k = 0; k < KK; ++k) w9[k] = sW[n][k];
        const float sinv = sInv[n];
        const float bias = sBias[n];

        float mean[4] = {0.f, 0.f, 0.f, 0.f};
        #pragma unroll
        for (int k = 0; k < KK; ++k) {
            const int kh = k / 3, kw = k - kh * 3;
            #pragma unroll
            for (int j = 0; j < 4; ++j)
                mean[j] += p[kh][j + kw] * w9[k];
        }
        #pragma unroll
        for (int j = 0; j < 4; ++j) mean[j] *= inv9;

        float* onb = obase + (size_t)((n * CC + c) * KK) * LL;
        #pragma unroll
        for (int k = 0; k < KK; ++k) {
            const int kh = k / 3, kw = k - kh * 3;
            vf4 o;
            #pragma unroll
            for (int j = 0; j < 4; ++j) {
                const float v = p[kh][j + kw] * w9[k];
                const float d = v - mean[j];
                o[j] = d * d * sinv + bias;
            }
            // streaming store: output (151 MB) >> L2 (32 MB), never re-read
            __builtin_nontemporal_store(o, (vf4*)(onb + (size_t)k * LL));
        }
    }
}

extern "C" void kernel_launch(void* const* d_in, const int* in_sizes, int n_in,
                              void* d_out, int out_size, void* d_ws, size_t ws_size,
                              hipStream_t stream) {
    const float* arr = (const float*)d_in[0];
    const float* Wt  = (const float*)d_in[1];
    const float* Bb  = (const float*)d_in[2];
    float* out = (float*)d_out;

    // total threads = B*C*H*(W/4) = 4*8*128*32 = 131072
    const int threads = 256;
    const int blocks = (BB * CC * HH * (WW / 4)) / threads;  // 512
    tvar_kernel<<<blocks, threads, 0, stream>>>(arr, Wt, Bb, out);
}